// Round 1
// baseline (290.950 us; speedup 1.0000x reference)
//
#include <hip/hip_runtime.h>

// Problem: B=16, T=128, H=56, W=56, C=8  (fp32)
//   active_sum[b,c]  = sum_{t<len,h,w} cam
//   total_sum[b,c]   = sum_{t,h,w} cam
//   blank = total - active
//   out[b] = mean_c huber(count, active_sum) + mean_c huber(0, blank) + 0.1*ttv
//   ttv = sum |masked[t] - masked[t-1]| over t=1..T-1, all b,h,w,c
//
// Memory-bound: 205.5 MB single pass. One read per element via per-thread
// t-walk with prev kept in registers.

#define NB 16
#define NT 128
#define NC 8
#define I4PBT 6272      // H*W*C/4 = 56*56*8/4
#define TCHUNKS 4
#define TCH 32          // NT / TCHUNKS
#define BLK 256
#define BLKS_PER_BT 25  // ceil(6272/256)

// ws layout (floats): [0..127] active_sum[b][c], [128..255] total_sum[b][c], [256] ttv

__global__ void __launch_bounds__(BLK)
ttv_reduce_kernel(const float* __restrict__ cam, const int* __restrict__ length,
                  float* __restrict__ ws) {
    const int blk = blockIdx.x;
    const int bt  = blk / BLKS_PER_BT;
    const int i4b = blk - bt * BLKS_PER_BT;
    const int b   = bt >> 2;     // / TCHUNKS
    const int tch = bt & 3;      // % TCHUNKS
    const int i4  = i4b * BLK + threadIdx.x;
    const bool live = (i4 < I4PBT);
    const int len = length[b];
    const int t0  = tch * TCH;

    float aA0=0.f,aA1=0.f,aA2=0.f,aA3=0.f;   // active sums (4 channels)
    float aT0=0.f,aT1=0.f,aT2=0.f,aT3=0.f;   // total sums
    float ttv = 0.f;

    if (live) {
        const float4* base = (const float4*)cam + (size_t)b * (size_t)(NT * I4PBT) + i4;
        float p0=0.f,p1=0.f,p2=0.f,p3=0.f;   // masked prev t-slice values
        if (t0 > 0 && (t0 - 1) < len) {
            float4 v = base[(size_t)(t0 - 1) * I4PBT];
            p0 = v.x; p1 = v.y; p2 = v.z; p3 = v.w;
        }
        #pragma unroll 4
        for (int t = t0; t < t0 + TCH; ++t) {
            float4 v = base[(size_t)t * I4PBT];
            aT0 += v.x; aT1 += v.y; aT2 += v.z; aT3 += v.w;
            float m0, m1, m2, m3;
            if (t < len) { m0 = v.x; m1 = v.y; m2 = v.z; m3 = v.w; }
            else         { m0 = 0.f; m1 = 0.f; m2 = 0.f; m3 = 0.f; }
            aA0 += m0; aA1 += m1; aA2 += m2; aA3 += m3;
            if (t > 0) {
                ttv += fabsf(m0 - p0) + fabsf(m1 - p1)
                     + fabsf(m2 - p2) + fabsf(m3 - p3);
            }
            p0 = m0; p1 = m1; p2 = m2; p3 = m3;
        }
    }

    // Wave butterfly reduce. XOR masks >= 2 preserve lane parity; lane parity
    // equals i4 parity (block base is even), which selects channels 0-3 vs 4-7.
    #pragma unroll
    for (int m = 32; m >= 2; m >>= 1) {
        aA0 += __shfl_xor(aA0, m); aA1 += __shfl_xor(aA1, m);
        aA2 += __shfl_xor(aA2, m); aA3 += __shfl_xor(aA3, m);
        aT0 += __shfl_xor(aT0, m); aT1 += __shfl_xor(aT1, m);
        aT2 += __shfl_xor(aT2, m); aT3 += __shfl_xor(aT3, m);
        ttv += __shfl_xor(ttv, m);
    }
    ttv += __shfl_xor(ttv, 1);   // full 64-lane reduce for the scalar

    __shared__ float lA[NC], lT[NC], lttv;
    if (threadIdx.x < NC) { lA[threadIdx.x] = 0.f; lT[threadIdx.x] = 0.f; }
    if (threadIdx.x == 0) lttv = 0.f;
    __syncthreads();

    const int lane = threadIdx.x & 63;
    if (lane < 2) {                      // lane0: channels 0-3, lane1: 4-7
        const int cb = lane << 2;
        atomicAdd(&lA[cb+0], aA0); atomicAdd(&lA[cb+1], aA1);
        atomicAdd(&lA[cb+2], aA2); atomicAdd(&lA[cb+3], aA3);
        atomicAdd(&lT[cb+0], aT0); atomicAdd(&lT[cb+1], aT1);
        atomicAdd(&lT[cb+2], aT2); atomicAdd(&lT[cb+3], aT3);
    }
    if (lane == 0) atomicAdd(&lttv, ttv);
    __syncthreads();

    if (threadIdx.x < NC) {
        atomicAdd(&ws[b * NC + threadIdx.x],           lA[threadIdx.x]);
        atomicAdd(&ws[NB * NC + b * NC + threadIdx.x], lT[threadIdx.x]);
    }
    if (threadIdx.x == NC) atomicAdd(&ws[2 * NB * NC], lttv);
}

__global__ void __launch_bounds__(NB * NC)
ttv_final_kernel(const float* __restrict__ count, const float* __restrict__ ws,
                 float* __restrict__ out) {
    const int tid = threadIdx.x;         // 0..127 -> (b,c)
    const int b = tid >> 3;
    const int c = tid & 7;

    const float a_sum = ws[tid];
    const float t_sum = ws[NB * NC + tid];
    const float blank = t_sum - a_sum;
    const float ttv   = ws[2 * NB * NC] * 0.1f;

    const float e1 = a_sum - count[tid];
    const float a1 = fabsf(e1);
    const float h1 = (a1 <= 1.f) ? 0.5f * e1 * e1 : a1 - 0.5f;
    const float a2 = fabsf(blank);
    const float h2 = (a2 <= 1.f) ? 0.5f * blank * blank : a2 - 0.5f;

    float h = h1 + h2;
    // reduce within each group of 8 lanes (groups are 8-aligned inside a wave)
    h += __shfl_xor(h, 4);
    h += __shfl_xor(h, 2);
    h += __shfl_xor(h, 1);

    if (c == 0) out[b] = h * 0.125f + ttv;
}

extern "C" void kernel_launch(void* const* d_in, const int* in_sizes, int n_in,
                              void* d_out, int out_size, void* d_ws, size_t ws_size,
                              hipStream_t stream) {
    const float* cam    = (const float*)d_in[0];
    const float* count  = (const float*)d_in[1];
    const int*   length = (const int*)d_in[2];
    float* out = (float*)d_out;
    float* ws  = (float*)d_ws;

    hipMemsetAsync(d_ws, 0, (2 * NB * NC + 1) * sizeof(float), stream);

    ttv_reduce_kernel<<<NB * TCHUNKS * BLKS_PER_BT, BLK, 0, stream>>>(cam, length, ws);
    ttv_final_kernel<<<1, NB * NC, 0, stream>>>(count, ws, out);
}

// Round 2
// 283.883 us; speedup vs baseline: 1.0249x; 1.0249x over previous
//
#include <hip/hip_runtime.h>

// Problem: B=16, T=128, H=56, W=56, C=8  (fp32)
//   active_sum[b,c] = sum_{t<len,h,w} cam ;  total_sum = sum over all t
//   out[b] = mean_c huber(count, active) + mean_c huber(0, total-active) + 0.1*ttv
//   ttv = sum_{t>=1} |masked[t]-masked[t-1]|  (masked = cam * (t<len))
//
// HBM-bound: 205.5 MB read once -> 33 us floor. Per-thread t-walk keeps the
// previous t-slice in registers so the temporal diff costs no extra traffic
// (only one boundary slice per t-chunk, +2.3%).

#define NB 16
#define NT 128
#define NC 8
#define I4PBT 6272      // H*W*C/4
#define TCHUNKS 4
#define TCH 32          // NT / TCHUNKS
#define BLK 256
#define BLKS_PER_BT 25  // ceil(6272/256)
#define TTV_SLOTS 64

// ws floats: [0..127] active[b][c], [128..255] total[b][c], [256..319] ttv slots

__global__ void __launch_bounds__(BLK)
ttv_reduce_kernel(const float* __restrict__ cam, const int* __restrict__ length,
                  float* __restrict__ ws) {
    const int blk = blockIdx.x;
    const int bt  = blk / BLKS_PER_BT;
    const int i4b = blk - bt * BLKS_PER_BT;
    const int b   = bt >> 2;
    const int tch = bt & 3;
    const int i4  = i4b * BLK + threadIdx.x;
    const bool live = (i4 < I4PBT);
    const int len = length[b];
    const int t0  = tch * TCH;

    float aA0=0.f,aA1=0.f,aA2=0.f,aA3=0.f;
    float aT0=0.f,aT1=0.f,aT2=0.f,aT3=0.f;
    float ttv = 0.f;

    if (live) {
        const float4* base = (const float4*)cam + (size_t)b * (size_t)(NT * I4PBT) + i4;
        float p0=0.f,p1=0.f,p2=0.f,p3=0.f;
        if (t0 > 0 && (t0 - 1) < len) {
            float4 v = base[(size_t)(t0 - 1) * I4PBT];
            p0 = v.x; p1 = v.y; p2 = v.z; p3 = v.w;
        }
        for (int tt = 0; tt < TCH; tt += 4) {
            // batch the 4 independent loads first -> >=4 outstanding VMEM
            float4 v[4];
            #pragma unroll
            for (int j = 0; j < 4; ++j)
                v[j] = base[(size_t)(t0 + tt + j) * I4PBT];
            #pragma unroll
            for (int j = 0; j < 4; ++j) {
                const int t = t0 + tt + j;
                aT0 += v[j].x; aT1 += v[j].y; aT2 += v[j].z; aT3 += v[j].w;
                float m0, m1, m2, m3;
                if (t < len) { m0 = v[j].x; m1 = v[j].y; m2 = v[j].z; m3 = v[j].w; }
                else         { m0 = 0.f;    m1 = 0.f;    m2 = 0.f;    m3 = 0.f;    }
                aA0 += m0; aA1 += m1; aA2 += m2; aA3 += m3;
                const float d = fabsf(m0 - p0) + fabsf(m1 - p1)
                              + fabsf(m2 - p2) + fabsf(m3 - p3);
                if (t > 0) ttv += d;
                p0 = m0; p1 = m1; p2 = m2; p3 = m3;
            }
        }
    }

    // Butterfly reduce; XOR masks >=2 preserve lane parity (= channel half,
    // since block-base i4 is even).
    #pragma unroll
    for (int m = 32; m >= 2; m >>= 1) {
        aA0 += __shfl_xor(aA0, m); aA1 += __shfl_xor(aA1, m);
        aA2 += __shfl_xor(aA2, m); aA3 += __shfl_xor(aA3, m);
        aT0 += __shfl_xor(aT0, m); aT1 += __shfl_xor(aT1, m);
        aT2 += __shfl_xor(aT2, m); aT3 += __shfl_xor(aT3, m);
        ttv += __shfl_xor(ttv, m);
    }
    ttv += __shfl_xor(ttv, 1);

    __shared__ float lA[NC], lT[NC], lttv;
    if (threadIdx.x < NC) { lA[threadIdx.x] = 0.f; lT[threadIdx.x] = 0.f; }
    if (threadIdx.x == 0) lttv = 0.f;
    __syncthreads();

    const int lane = threadIdx.x & 63;
    if (lane < 2) {                      // lane0: ch 0-3, lane1: ch 4-7
        const int cb = lane << 2;
        atomicAdd(&lA[cb+0], aA0); atomicAdd(&lA[cb+1], aA1);
        atomicAdd(&lA[cb+2], aA2); atomicAdd(&lA[cb+3], aA3);
        atomicAdd(&lT[cb+0], aT0); atomicAdd(&lT[cb+1], aT1);
        atomicAdd(&lT[cb+2], aT2); atomicAdd(&lT[cb+3], aT3);
    }
    if (lane == 0) atomicAdd(&lttv, ttv);
    __syncthreads();

    if (threadIdx.x < NC) {
        atomicAdd(&ws[b * NC + threadIdx.x],           lA[threadIdx.x]);
        atomicAdd(&ws[NB * NC + b * NC + threadIdx.x], lT[threadIdx.x]);
    }
    if (threadIdx.x == NC)
        atomicAdd(&ws[2 * NB * NC + (blk & (TTV_SLOTS - 1))], lttv);
}

__global__ void __launch_bounds__(NB * NC)
ttv_final_kernel(const float* __restrict__ count, const float* __restrict__ ws,
                 float* __restrict__ out) {
    __shared__ float sttv;
    const int tid = threadIdx.x;         // 0..127
    if (tid < TTV_SLOTS) {
        float v = ws[2 * NB * NC + tid];
        #pragma unroll
        for (int m = 32; m >= 1; m >>= 1) v += __shfl_xor(v, m);
        if (tid == 0) sttv = v;
    }
    __syncthreads();

    const int b = tid >> 3;
    const int c = tid & 7;
    const float a_sum = ws[tid];
    const float t_sum = ws[NB * NC + tid];
    const float blank = t_sum - a_sum;

    const float e1 = a_sum - count[tid];
    const float a1 = fabsf(e1);
    const float h1 = (a1 <= 1.f) ? 0.5f * e1 * e1 : a1 - 0.5f;
    const float a2 = fabsf(blank);
    const float h2 = (a2 <= 1.f) ? 0.5f * blank * blank : a2 - 0.5f;

    float h = h1 + h2;
    h += __shfl_xor(h, 4);
    h += __shfl_xor(h, 2);
    h += __shfl_xor(h, 1);

    if (c == 0) out[b] = h * 0.125f + sttv * 0.1f;
    (void)b;
}

extern "C" void kernel_launch(void* const* d_in, const int* in_sizes, int n_in,
                              void* d_out, int out_size, void* d_ws, size_t ws_size,
                              hipStream_t stream) {
    const float* cam    = (const float*)d_in[0];
    const float* count  = (const float*)d_in[1];
    const int*   length = (const int*)d_in[2];
    float* out = (float*)d_out;
    float* ws  = (float*)d_ws;

    hipMemsetAsync(d_ws, 0, (2 * NB * NC + TTV_SLOTS) * sizeof(float), stream);

    ttv_reduce_kernel<<<NB * TCHUNKS * BLKS_PER_BT, BLK, 0, stream>>>(cam, length, ws);
    ttv_final_kernel<<<1, NB * NC, 0, stream>>>(count, ws, out);
}